// Round 6
// baseline (223.488 us; speedup 1.0000x reference)
//
#include <hip/hip_runtime.h>
#include <hip/hip_fp16.h>

#define N_    8
#define CIN   128
#define COUT  128
#define H_    128
#define W_    128
#define HO    126
#define WO    126
#define PIXPER (HO*WO)            // 15876
#define TOTPIX (N_*PIXPER)        // 127008
#define PT    128                 // pixels per block
#define BLKPERIMG 125
#define NBLK  (N_*BLKPERIMG)      // 1000
#define SSTR  136                 // fp16 stride of sS px-row (+16B pad)

typedef _Float16 f16x8 __attribute__((ext_vector_type(8)));
typedef _Float16 f16x4 __attribute__((ext_vector_type(4)));
typedef float    f32x4 __attribute__((ext_vector_type(4)));

union U4H {
    uint4   u;
    __half2 h[4];
    f16x8   f;
};

// ---------------------------------------------------------------------------
// transpose_in v2: [N][C][HW] fp32 -> [N][HW][C] fp16.
// Tile 32c x 128hw. Reads 512B/c-row; LDS fp32 [32][129]; writes are exact
// 64B lines (32 px-rows x 64B per instr). 4096 blocks.
// ---------------------------------------------------------------------------
__global__ __launch_bounds__(256) void transpose_in_kernel(
    const float* __restrict__ in, _Float16* __restrict__ in_cl)
{
    __shared__ float tile[32][129];
    int bid = blockIdx.x;
    int hwt = bid & 127;          // HW/128
    int ct  = (bid >> 7) & 3;     // C/32
    int n   = bid >> 9;           // N
    int t   = threadIdx.x;

    // read: c = (t>>5)+8i (32 rows), f4 = t&31 (128 floats per row)
    int f4 = t & 31;
    const float* src = in + ((size_t)(n * CIN + ct * 32) * 16384) + hwt * 128;
#pragma unroll
    for (int i = 0; i < 4; ++i) {
        int c = (t >> 5) + i * 8;
        float4 v = *(const float4*)(src + (size_t)c * 16384 + f4 * 4);
        *(float4*)&tile[c][f4 * 4] = v;    // lanes 0-7 tile all 32 banks
    }
    __syncthreads();
    // write: hw = t>>1, c16 = (t&1)*16 ; 32B per thread, 64B per lane-pair
    int hw  = t >> 1;
    int c16 = (t & 1) * 16;
    _Float16* dst = in_cl + ((size_t)(n * 16384 + hwt * 128 + hw) * 128) + ct * 32 + c16;
    f16x8 lo, hi;
#pragma unroll
    for (int j = 0; j < 8; ++j) lo[j] = (_Float16)tile[c16 + j][hw];
#pragma unroll
    for (int j = 0; j < 8; ++j) hi[j] = (_Float16)tile[c16 + 8 + j][hw];
    *(f16x8*)dst       = lo;
    *(f16x8*)(dst + 8) = hi;
}

// ---------------------------------------------------------------------------
// transpose_w v2: w[O][C][3][3] fp32 -> wt2 in MFMA A-frag order:
// wt2[((tap*8+mt)*4+ks)*512 + lane*8 + d], lane=quad*16+l15,
// o=mt*16+l15, c=ks*32+quad*8+d  -> frag load = 1KB lane-contiguous.
// ---------------------------------------------------------------------------
__global__ void transpose_w_kernel(const float* __restrict__ w, _Float16* __restrict__ wt2) {
    int t = blockIdx.x * 256 + threadIdx.x;   // 16384
    int o = t >> 7, c = t & 127;
    int mt = o >> 4, l15 = o & 15;
    int ks = c >> 5, quad = (c >> 3) & 3, d = c & 7;
    int lane = quad * 16 + l15;
    const float* s = w + (size_t)(o * 128 + c) * 9;
#pragma unroll
    for (int tap = 0; tap < 9; ++tap)
        wt2[(size_t)((tap * 8 + mt) * 4 + ks) * 512 + lane * 8 + d] = (_Float16)s[tap];
}

// ---------------------------------------------------------------------------
// Main kernel. Block = 128 px x 128 o, 4 waves, 3 blocks/CU (LDS 47.1KB).
// Prologue: per-px packed params — sKH[kh][px]={row0,row1,a0h,a1h},
// sKW[kw][px]={off0,off1,b0h,b1h}; validity folded into a/b weights.
// Phase A: row-coalesced gather + lerp -> sS (2 broadcast LDS reads + adds).
// Phase B: A-frags from global wt2 (frag-order, L1-resident), B from sS.
// ---------------------------------------------------------------------------
__global__ __launch_bounds__(256, 3) void adc_main(
    const _Float16* __restrict__ in_cl, const _Float16* __restrict__ wt2,
    const float* __restrict__ rates, const float* __restrict__ bias,
    float* __restrict__ out)
{
    __shared__ __align__(16) _Float16 sS[PT * SSTR];    // 34816 B
    __shared__ uint4 sKH[3 * PT];                       // 6144 B
    __shared__ uint4 sKW[3 * PT];                       // 6144 B

    const int t    = threadIdx.x;
    const int lane = t & 63;
    const int wv   = t >> 6;
    const int l15  = lane & 15;
    const int quad = lane >> 4;

    const int n     = blockIdx.x & 7;
    const int pbase = (blockIdx.x >> 3) * PT;
    const unsigned nbase = (unsigned)n << 14;

    // ---- prologue: packed per-px params (validity folded into weights) ----
    if (t < PT) {
        int rem = min(pbase + t, PIXPER - 1);
        int ho = rem / WO, wo = rem - ho * WO;
        const float sc = 32.0f / 126.0f;
        float sy = fminf(fmaxf(((float)ho + 0.5f) * sc - 0.5f, 0.0f), 31.0f);
        float sx = fminf(fmaxf(((float)wo + 0.5f) * sc - 0.5f, 0.0f), 31.0f);
        int ry0 = (int)sy, rx0 = (int)sx;
        int ry1 = min(ry0 + 1, 31), rx1 = min(rx0 + 1, 31);
        float rwy = sy - (float)ry0, rwx = sx - (float)rx0;
        float r = rates[ry0 * 32 + rx0] * (1.0f - rwy) * (1.0f - rwx)
                + rates[ry0 * 32 + rx1] * (1.0f - rwy) * rwx
                + rates[ry1 * 32 + rx0] * rwy * (1.0f - rwx)
                + rates[ry1 * 32 + rx1] * rwy * rwx;
#pragma unroll
        for (int k = 0; k < 3; ++k) {
            // vertical
            float fy  = (float)ho + (float)k * r;   // exact int when k==0
            float y0f = floorf(fy);
            int   y0  = (int)y0f;
            float wy  = fy - y0f;
            float a0  = (y0 <= H_ - 1) ? (1.0f - wy) : 0.0f;
            float a1  = (y0 <= H_ - 2) ? wy : 0.0f;
            int yc0 = min(y0, H_ - 1), yc1 = min(y0 + 1, H_ - 1);
            uint4 P;
            P.x = (nbase + (unsigned)(yc0 * W_)) << 7;
            P.y = (nbase + (unsigned)(yc1 * W_)) << 7;
            P.z = __builtin_bit_cast(unsigned, __float2half2_rn(a0));
            P.w = __builtin_bit_cast(unsigned, __float2half2_rn(a1));
            sKH[k * PT + t] = P;
            // horizontal
            float fx  = (float)wo + (float)k * r;
            float x0f = floorf(fx);
            int   x0  = (int)x0f;
            float wx  = fx - x0f;
            float b0  = (x0 <= W_ - 1) ? (1.0f - wx) : 0.0f;
            float b1  = (x0 <= W_ - 2) ? wx : 0.0f;
            int xc0 = min(x0, W_ - 1), xc1 = min(x0 + 1, W_ - 1);
            uint4 Q;
            Q.x = (unsigned)xc0 << 7;
            Q.y = (unsigned)xc1 << 7;
            Q.z = __builtin_bit_cast(unsigned, __float2half2_rn(b0));
            Q.w = __builtin_bit_cast(unsigned, __float2half2_rn(b1));
            sKW[k * PT + t] = Q;
        }
    }

    f32x4 acc[8][2];
    const f32x4 zero = {0.0f, 0.0f, 0.0f, 0.0f};
#pragma unroll
    for (int i = 0; i < 8; ++i) { acc[i][0] = zero; acc[i][1] = zero; }

    __syncthreads();

    const int grp = t >> 4;        // 16 px-groups of 8
    const int gl  = t & 15;        // channel chunk: gl*8 .. gl*8+8
    const unsigned lo = (unsigned)(gl * 8);

#pragma unroll
    for (int tap = 0; tap < 9; ++tap) {
        const int kh = tap / 3;            // compile-time after unroll
        const int kw = tap - kh * 3;

        // ---- phase A: coalesced gather + lerp -> sS ----
#pragma unroll
        for (int j = 0; j < 8; ++j) {
            int px = grp * 8 + j;
            uint4 P = sKH[kh * PT + px];   // broadcast within 16-lane group
            uint4 Q = sKW[kw * PT + px];
            unsigned aA = P.x + Q.x + lo;
            U4H A, B, C, D, S;
            A.u = *(const uint4*)(in_cl + aA);
            if (kw != 0) B.u = *(const uint4*)(in_cl + (P.x + Q.y + lo));
            if (kh != 0) C.u = *(const uint4*)(in_cl + (P.y + Q.x + lo));
            if (kh != 0 && kw != 0) D.u = *(const uint4*)(in_cl + (P.y + Q.y + lo));
            if (kh == 0 && kw == 0) {
                S.u = A.u;                 // exact copy, weight == 1
            } else {
                __half2 a0h = __builtin_bit_cast(__half2, P.z);
                __half2 a1h = __builtin_bit_cast(__half2, P.w);
                __half2 b0h = __builtin_bit_cast(__half2, Q.z);
                __half2 b1h = __builtin_bit_cast(__half2, Q.w);
                __half2 w00v = __hmul2(a0h, b0h);
                __half2 w01v = (kw != 0) ? __hmul2(a0h, b1h) : __half2{};
                __half2 w10v = (kh != 0) ? __hmul2(a1h, b0h) : __half2{};
                __half2 w11v = (kh != 0 && kw != 0) ? __hmul2(a1h, b1h) : __half2{};
#pragma unroll
                for (int d = 0; d < 4; ++d) {
                    __half2 s = __hmul2(A.h[d], w00v);
                    if (kw != 0)            s = __hfma2(B.h[d], w01v, s);
                    if (kh != 0)            s = __hfma2(C.h[d], w10v, s);
                    if (kh != 0 && kw != 0) s = __hfma2(D.h[d], w11v, s);
                    S.h[d] = s;
                }
            }
            *(f16x8*)&sS[px * SSTR + gl * 8] = S.f;
        }
        __syncthreads();

        // ---- phase B: MFMA; A-frags from global (frag-order), B from sS ----
        const _Float16* wbase = wt2 + (size_t)tap * 16384 + lane * 8;
#pragma unroll
        for (int ks = 0; ks < 4; ++ks) {
            f16x8 b0 = *(const f16x8*)&sS[(wv * 32 +      l15) * SSTR + ks * 32 + quad * 8];
            f16x8 b1 = *(const f16x8*)&sS[(wv * 32 + 16 + l15) * SSTR + ks * 32 + quad * 8];
#pragma unroll
            for (int mt = 0; mt < 8; ++mt) {
                f16x8 af = *(const f16x8*)(wbase + (mt * 4 + ks) * 512);
                acc[mt][0] = __builtin_amdgcn_mfma_f32_16x16x32_f16(af, b0, acc[mt][0], 0, 0, 0);
                acc[mt][1] = __builtin_amdgcn_mfma_f32_16x16x32_f16(af, b1, acc[mt][1], 0, 0, 0);
            }
        }
        __syncthreads();
    }

    // ---- epilogue: direct strided stores (R3-proven) ----
#pragma unroll
    for (int pt = 0; pt < 2; ++pt) {
        int p    = (wv << 5) + (pt << 4) + l15;
        int prel = pbase + p;
        int rem2 = min(prel, PIXPER - 1);
        float* obase = out + (size_t)n * (COUT * PIXPER) + rem2;
        if (prel < PIXPER) {
#pragma unroll
            for (int mt = 0; mt < 8; ++mt) {
                int o0 = (mt << 4) + (quad << 2);
                float4 bs = *(const float4*)(bias + o0);
                f32x4 a0 = acc[mt][pt];
                obase[(size_t)(o0 + 0) * PIXPER] = a0[0] + bs.x;
                obase[(size_t)(o0 + 1) * PIXPER] = a0[1] + bs.y;
                obase[(size_t)(o0 + 2) * PIXPER] = a0[2] + bs.z;
                obase[(size_t)(o0 + 3) * PIXPER] = a0[3] + bs.w;
            }
        }
    }
}

// ---------------------------------------------------------------------------
extern "C" void kernel_launch(void* const* d_in, const int* in_sizes, int n_in,
                              void* d_out, int out_size, void* d_ws, size_t ws_size,
                              hipStream_t stream) {
    const float* inputs = (const float*)d_in[0];   // [8,128,128,128]
    const float* weight = (const float*)d_in[1];   // [128,128,3,3]
    const float* rates  = (const float*)d_in[2];   // [1,1,32,32]
    const float* bias   = (const float*)d_in[3];   // [128]
    float* out = (float*)d_out;                    // [8,128,126,126]

    char* ws = (char*)d_ws;
    _Float16* in_cl = (_Float16*)ws;                         // 33,554,432 B
    _Float16* wt2   = (_Float16*)(ws + 33554432);            //    294,912 B

    transpose_w_kernel<<<64, 256, 0, stream>>>(weight, wt2);
    transpose_in_kernel<<<4096, 256, 0, stream>>>(inputs, in_cl);
    adc_main<<<NBLK, 256, 0, stream>>>(in_cl, wt2, rates, bias, out);
}